// Round 15
// baseline (298.292 us; speedup 1.0000x reference)
//
#include <hip/hip_runtime.h>
#include <stdint.h>
#include <stddef.h>

#define IN_F    4096
#define OUT_F   4096
#define MTOK    8192      // 4 * 2048 tokens
#define RANK    16
#define SCALING 2.0f      // alpha/rank = 32/16

typedef __attribute__((ext_vector_type(8))) short          bf16x8;
typedef __attribute__((ext_vector_type(4))) float          f32x4;
typedef __attribute__((ext_vector_type(4))) float          fl4;
typedef __attribute__((ext_vector_type(4))) unsigned short u16x4;
typedef __attribute__((ext_vector_type(8))) unsigned short u16x8;

static __device__ __forceinline__ unsigned short f2bf(float f) {
  union { float f; uint32_t u; } v; v.f = f;
  return (unsigned short)((v.u + 0x7fffu + ((v.u >> 16) & 1u)) >> 16);  // RNE
}

static __device__ __forceinline__ void gload16(const void* g, void* l) {
  __builtin_amdgcn_global_load_lds(
      (const __attribute__((address_space(1))) uint32_t*)g,
      (__attribute__((address_space(3))) uint32_t*)l,
      16, 0, 0);
}

// raw s_barrier is IntrNoMem -> fence with sched_barrier(0) on both sides
#define SBAR() __builtin_amdgcn_sched_barrier(0)
#define BARRIER() do { SBAR(); __builtin_amdgcn_s_barrier(); SBAR(); } while (0)

// ---------------------------------------------------------------------------
// fused prep: blocks [0, OUT_F/4) merge 4 W-rows each -> Weff bf16;
//             blocks [OUT_F/4, ...) convert x f32 -> bf16
// ---------------------------------------------------------------------------
#define MERGE_BLKS (OUT_F / 4)   // 1024

__global__ void prep_kernel(const float* __restrict__ x,
                            const float* __restrict__ W,
                            const float* __restrict__ lA,
                            const float* __restrict__ lB,
                            unsigned short* __restrict__ Weff,
                            unsigned short* __restrict__ xb) {
  __shared__ float Bs[4][RANK];
  if (blockIdx.x < MERGE_BLKS) {
    const int o0 = blockIdx.x * 4;
    if (threadIdx.x < 4 * RANK)
      Bs[threadIdx.x >> 4][threadIdx.x & 15] =
          lB[o0 * RANK + threadIdx.x] * SCALING;
    __syncthreads();
#pragma unroll
    for (int it = 0; it < 4; ++it) {
      const int c = threadIdx.x * 4 + it * 1024;
      fl4 w0 = *(const fl4*)(W + (size_t)(o0 + 0) * IN_F + c);
      fl4 w1 = *(const fl4*)(W + (size_t)(o0 + 1) * IN_F + c);
      fl4 w2 = *(const fl4*)(W + (size_t)(o0 + 2) * IN_F + c);
      fl4 w3 = *(const fl4*)(W + (size_t)(o0 + 3) * IN_F + c);
#pragma unroll
      for (int r = 0; r < RANK; ++r) {
        const fl4 a = *(const fl4*)(lA + (size_t)r * IN_F + c);
        const float b0 = Bs[0][r], b1 = Bs[1][r], b2 = Bs[2][r], b3 = Bs[3][r];
#pragma unroll
        for (int e = 0; e < 4; ++e) {
          w0[e] += b0 * a[e]; w1[e] += b1 * a[e];
          w2[e] += b2 * a[e]; w3[e] += b3 * a[e];
        }
      }
      u16x4 p0, p1, p2, p3;
#pragma unroll
      for (int e = 0; e < 4; ++e) {
        p0[e] = f2bf(w0[e]); p1[e] = f2bf(w1[e]);
        p2[e] = f2bf(w2[e]); p3[e] = f2bf(w3[e]);
      }
      *(u16x4*)(Weff + (size_t)(o0 + 0) * IN_F + c) = p0;
      *(u16x4*)(Weff + (size_t)(o0 + 1) * IN_F + c) = p1;
      *(u16x4*)(Weff + (size_t)(o0 + 2) * IN_F + c) = p2;
      *(u16x4*)(Weff + (size_t)(o0 + 3) * IN_F + c) = p3;
    }
  } else {
    const size_t i = ((size_t)(blockIdx.x - MERGE_BLKS) * 256 + threadIdx.x) * 8;
    const fl4 a = *(const fl4*)(x + i);
    const fl4 b = *(const fl4*)(x + i + 4);
    u16x8 p;
    p[0] = f2bf(a[0]); p[1] = f2bf(a[1]); p[2] = f2bf(a[2]); p[3] = f2bf(a[3]);
    p[4] = f2bf(b[0]); p[5] = f2bf(b[1]); p[6] = f2bf(b[2]); p[7] = f2bf(b[3]);
    *(u16x8*)(xb + i) = p;
  }
}

// ---------------------------------------------------------------------------
// 256x256 tile, BK=64, 8 waves (2Mx4N), TWO phases per tile (R15 = R14 fixed):
//  phA: {read A-h0+b0 | stage A0,B0(t+1) | vmcnt(4) | BAR | Q00 | read b1 | Q01}
//  phB: {read A-h1 | stage B1,A1(t+1) | vmcnt(4)+lgkmcnt(0) | BAR | Q11 | Q10}
// Full inductive license chain (each STAGE = 2 loads; queue FIFO):
//   prologue: stage 8 (t0), vmcnt(4)     -> A0,B0(t0) confirmed.
//   t:phA:    8 outstanding, vmcnt(4)    -> B1,A1(t)  confirmed
//             (licenses phA's post-BAR b1 read and phB's A-h1 read).
//   t:phB:    8 outstanding, vmcnt(4)    -> A0,B0(t+1) confirmed
//             (licenses t+1:phA's pre-BAR A-h0+b0 reads).  [R14 BUG: missing]
// WAR keystone: phB's pre-barrier ds_reads of buf BU are drained by
// lgkmcnt(0) before phB's barrier; t+1:phA's staging into BU issues only
// after crossing that barrier. Tail (PF=false): phA vmcnt(0) drains all.
// ---------------------------------------------------------------------------
__global__ __launch_bounds__(512, 2) void gemm8p_kernel(
    const unsigned short* __restrict__ X,    // [8192][4096] bf16
    const unsigned short* __restrict__ Wf,   // [4096][4096] bf16
    float* __restrict__ Out) {
  __shared__ char lds[131072];
  const int tid  = threadIdx.x;
  const int lane = tid & 63;
  const int wave = tid >> 6;
  const int wr = wave >> 2;            // 0..1 (M half)
  const int wc = wave & 3;             // 0..3 (N strip)
  const int fr = lane & 15;
  const int fq = lane >> 4;

  // XCD chunking: each XCD owns 4 consecutive M-tiles x all 16 N-tiles
  const int bid = blockIdx.x;
  const int tm  = (bid & 7) * 4 + ((bid >> 3) & 3);   // 0..31
  const int tn  = bid >> 5;                           // 0..15
  const int m0 = tm << 8;
  const int n0 = tn << 8;

  const unsigned short* Ag = X  + (size_t)m0 * IN_F;
  const unsigned short* Bg = Wf + (size_t)n0 * IN_F;

  // staging lane constants: window = 8 rows x 64 cols = 1024B, slot = 16B
  const int rIW = lane >> 3;                    // row within 8-row window
  const int csw = ((lane & 7) ^ rIW) << 3;      // pre-swizzled source col (elems)

  // ds_read address parts (bytes)
  const int aBase = wr * 16384 + fr * 128;
  const int bBase = 65536 + (wc >> 1) * 16384 + (wc & 1) * 8192 + fr * 128;
  const int cA0 = (fq << 4) ^ ((fr & 7) << 4);  // kk=0 swizzled colbyte
  const int cA1 = cA0 ^ 64;                     // kk=1

  // A chunk C: each wave stages 16 rows of its half-interleaved chunk
#define STAGE_A(C, BUF, K) do {                                                \
    const int _rh = (C) * 64 + (wave & 3) * 16;                                \
    const int _r0 = (wave >> 2) * 128 + _rh + rIW;                             \
    char* _d = lds + (BUF) * 32768 + (wave >> 2) * 16384 + _rh * 128 +         \
               (lane << 4);                                                    \
    gload16(Ag + (size_t)_r0 * IN_F + (K) + csw, _d);                          \
    gload16(Ag + (size_t)(_r0 + 8) * IN_F + (K) + csw, _d + 1024);             \
  } while (0)

  // B chunk C: strip = wave>>1; rows C*32 + (wave&1)*16 .. +15 of that strip
#define STAGE_B(C, BUF, K) do {                                                \
    const int _s  = wave >> 1;                                                 \
    const int _rh = (_s & 1) * 64 + (C) * 32 + (wave & 1) * 16;                \
    const int _r0 = (_s >> 1) * 128 + _rh + rIW;                               \
    char* _d = lds + 65536 + (BUF) * 32768 + (_s >> 1) * 16384 + _rh * 128 +   \
               (lane << 4);                                                    \
    gload16(Bg + (size_t)_r0 * IN_F + (K) + csw, _d);                          \
    gload16(Bg + (size_t)(_r0 + 8) * IN_F + (K) + csw, _d + 1024);             \
  } while (0)

#define LDA(BUF, M, KK) (*(const bf16x8*)(lds + (BUF) * 32768 + aBase + (M) * 2048 + (KK)))
#define LDB(BUF, N, KK) (*(const bf16x8*)(lds + (BUF) * 32768 + bBase + (N) * 2048 + (KK)))

#define MFMA_Q(MB, NB, BR)                                                     \
  _Pragma("unroll")                                                            \
  for (int mi = 0; mi < 4; ++mi)                                               \
    _Pragma("unroll")                                                          \
    for (int ni = 0; ni < 2; ++ni) {                                           \
      acc[(MB)+mi][(NB)+ni] = __builtin_amdgcn_mfma_f32_16x16x32_bf16(a[mi*2],   BR[ni*2],   acc[(MB)+mi][(NB)+ni], 0, 0, 0); \
      acc[(MB)+mi][(NB)+ni] = __builtin_amdgcn_mfma_f32_16x16x32_bf16(a[mi*2+1], BR[ni*2+1], acc[(MB)+mi][(NB)+ni], 0, 0, 0); \
    }

  // BU = compile-time buffer of tile t; NB = BU^1; KN = k of t+1; PF bool
#define TILE(BU, NB, KN, PF)                                                   \
  do {                                                                         \
    /* ======== phase A ======== */                                            \
    _Pragma("unroll")                                                          \
    for (int mi = 0; mi < 4; ++mi) { a[mi*2] = LDA(BU, mi, cA0); a[mi*2+1] = LDA(BU, mi, cA1); } \
    _Pragma("unroll")                                                          \
    for (int ni = 0; ni < 2; ++ni) { b0[ni*2] = LDB(BU, ni, cA0); b0[ni*2+1] = LDB(BU, ni, cA1); } \
    if (PF) { STAGE_A(0, NB, KN); STAGE_B(0, NB, KN);                          \
              asm volatile("s_waitcnt vmcnt(4)" ::: "memory"); }               \
    else    { asm volatile("s_waitcnt vmcnt(0)" ::: "memory"); }               \
    BARRIER();                                                                 \
    __builtin_amdgcn_s_setprio(1);                                             \
    MFMA_Q(0, 0, b0)                                                           \
    __builtin_amdgcn_s_setprio(0);                                             \
    _Pragma("unroll")                                                          \
    for (int ni = 0; ni < 2; ++ni) { b1[ni*2] = LDB(BU, 2+ni, cA0); b1[ni*2+1] = LDB(BU, 2+ni, cA1); } \
    __builtin_amdgcn_s_setprio(1);                                             \
    MFMA_Q(0, 2, b1)                                                           \
    __builtin_amdgcn_s_setprio(0);                                             \
    /* ======== phase B ======== */                                            \
    _Pragma("unroll")                                                          \
    for (int mi = 0; mi < 4; ++mi) { a[mi*2] = LDA(BU, 4+mi, cA0); a[mi*2+1] = LDA(BU, 4+mi, cA1); } \
    if (PF) { STAGE_B(1, NB, KN); STAGE_A(1, NB, KN);                          \
              asm volatile("s_waitcnt vmcnt(4) lgkmcnt(0)" ::: "memory"); }    \
    else    { asm volatile("s_waitcnt lgkmcnt(0)" ::: "memory"); }             \
    BARRIER();                                                                 \
    __builtin_amdgcn_s_setprio(1);                                             \
    MFMA_Q(4, 2, b1)                                                           \
    MFMA_Q(4, 0, b0)                                                           \
    __builtin_amdgcn_s_setprio(0);                                             \
  } while (0)

  f32x4 acc[8][4];
#pragma unroll
  for (int i = 0; i < 8; ++i)
#pragma unroll
    for (int j = 0; j < 4; ++j) acc[i][j] = (f32x4){0.f, 0.f, 0.f, 0.f};

  bf16x8 a[8], b0[4], b1[4];

  // prologue: tile 0 -> buf 0, issue order [A0, B0, B1, A1];
  // vmcnt(4) ensures A0,B0(t0) landed before phA's reads.
  STAGE_A(0, 0, 0); STAGE_B(0, 0, 0); STAGE_B(1, 0, 0); STAGE_A(1, 0, 0);
  asm volatile("s_waitcnt vmcnt(4)" ::: "memory");
  BARRIER();

  for (int tt = 0; tt < 32; ++tt) {
    const int k1 = (tt << 7) + 64;        // always < IN_F
    const int k2 = k1 + 64;               // == IN_F at tt==31
    TILE(0, 1, k1, true);
    TILE(1, 0, k2, (k2 < IN_F));
  }

  // ---- epilogue: C[row = m*16+fq*4+j][col = n*16+fr] ----
#pragma unroll
  for (int mi = 0; mi < 8; ++mi) {
    const int row0 = m0 + wr * 128 + mi * 16 + fq * 4;
#pragma unroll
    for (int ni = 0; ni < 4; ++ni) {
      const int col = n0 + wc * 64 + ni * 16 + fr;
#pragma unroll
      for (int j = 0; j < 4; ++j)
        Out[(size_t)(row0 + j) * OUT_F + col] = acc[mi][ni][j];
    }
  }
#undef STAGE_A
#undef STAGE_B
#undef LDA
#undef LDB
#undef MFMA_Q
#undef TILE
}

// ---------------------------------------------------------------------------
// mid-ws fallback: 128^2 m97-structure GEMM reading f32 x directly
// ---------------------------------------------------------------------------
__global__ __launch_bounds__(256) void gemm_f32x_kernel(
    const float* __restrict__ X,
    const unsigned short* __restrict__ Weff,
    float* __restrict__ Out) {
  __shared__ unsigned short As[128][32];
  __shared__ unsigned short Bs[128][32];

  const int tid  = threadIdx.x;
  const int lane = tid & 63;
  const int wave = tid >> 6;
  const int wr = wave >> 1, wc = wave & 1;
  const int fr = lane & 15, fq = lane >> 4;

  const int bid = blockIdx.x;
  const int m0 = (bid & 63) * 128;
  const int n0 = (bid >> 6) * 128;

  f32x4 acc[4][4];
#pragma unroll
  for (int i = 0; i < 4; ++i)
#pragma unroll
    for (int j = 0; j < 4; ++j) acc[i][j] = (f32x4){0.f, 0.f, 0.f, 0.f};

  const int srow = tid >> 2;
  const int sseg = tid & 3;

  for (int k0 = 0; k0 < IN_F; k0 += 32) {
    if (k0) __syncthreads();
    {
      const unsigned short* gB = Weff + (size_t)(n0 + srow) * IN_F + k0 + sseg * 8;
      gload16(gB, &Bs[srow][sseg * 8]);
      gload16(gB + (size_t)64 * IN_F, &Bs[64 + srow][sseg * 8]);
    }
#pragma unroll
    for (int it = 0; it < 4; ++it) {
      const int c   = tid + it * 256;
      const int row = c >> 3;
      const int c4  = (c & 7) * 4;
      const fl4 v = *(const fl4*)(X + (size_t)(m0 + row) * IN_F + k0 + c4);
      u16x4 p;
      p[0] = f2bf(v[0]); p[1] = f2bf(v[1]); p[2] = f2bf(v[2]); p[3] = f2bf(v[3]);
      *(u16x4*)&As[row][c4] = p;
    }
    __syncthreads();

    bf16x8 af[4], bfm[4];
#pragma unroll
    for (int m = 0; m < 4; ++m)
      af[m] = *(const bf16x8*)&As[wr * 64 + m * 16 + fr][fq * 8];
#pragma unroll
    for (int n = 0; n < 4; ++n)
      bfm[n] = *(const bf16x8*)&Bs[wc * 64 + n * 16 + fr][fq * 8];
#pragma unroll
    for (int m = 0; m < 4; ++m)
#pragma unroll
      for (int n = 0; n < 4; ++n)
        acc[m][n] = __builtin_amdgcn_mfma_f32_16x16x32_bf16(af[m], bfm[n], acc[m][n], 0, 0, 0);
  }

#pragma unroll
  for (int m = 0; m < 4; ++m) {
    const int row0 = m0 + wr * 64 + m * 16 + fq * 4;
#pragma unroll
    for (int n = 0; n < 4; ++n) {
      const int col = n0 + wc * 64 + n * 16 + fr;
#pragma unroll
      for (int j = 0; j < 4; ++j)
        Out[(size_t)(row0 + j) * OUT_F + col] = acc[m][n][j];
    }
  }
}

// ---------------------------------------------------------------------------
// never-path fallbacks (tiny ws)
// ---------------------------------------------------------------------------
__global__ void lora_r_kernel(const float* __restrict__ x,
                              const float* __restrict__ lA,
                              float* __restrict__ r) {
  const int idx = blockIdx.x * 256 + threadIdx.x;
  const int m = idx / RANK, rr = idx % RANK;
  float acc = 0.f;
  for (int k = 0; k < IN_F; ++k)
    acc += x[(size_t)m * IN_F + k] * lA[(size_t)rr * IN_F + k];
  r[idx] = acc * SCALING;
}

__global__ void naive_out_kernel(const float* __restrict__ x,
                                 const float* __restrict__ W,
                                 const float* __restrict__ lB,
                                 const float* __restrict__ r,
                                 float* __restrict__ out) {
  const size_t idx = (size_t)blockIdx.x * 256 + threadIdx.x;
  const int m = (int)(idx / OUT_F), n = (int)(idx % OUT_F);
  float acc = 0.f;
  for (int k = 0; k < IN_F; ++k)
    acc += x[(size_t)m * IN_F + k] * W[(size_t)n * IN_F + k];
#pragma unroll
  for (int rr = 0; rr < RANK; ++rr)
    acc += r[(size_t)m * RANK + rr] * lB[(size_t)n * RANK + rr];
  out[idx] = acc;
}

// ---------------------------------------------------------------------------
extern "C" void kernel_launch(void* const* d_in, const int* in_sizes, int n_in,
                              void* d_out, int out_size, void* d_ws, size_t ws_size,
                              hipStream_t stream) {
  const float* x  = (const float*)d_in[0];
  const float* W  = (const float*)d_in[1];
  const float* lA = (const float*)d_in[2];
  const float* lB = (const float*)d_in[3];
  float* out = (float*)d_out;

  const size_t weff_bytes = (size_t)OUT_F * IN_F * 2;   // 32 MiB
  const size_t xb_bytes   = (size_t)MTOK * IN_F * 2;    // 64 MiB

  if (ws_size >= weff_bytes + xb_bytes) {
    unsigned short* Weff = (unsigned short*)d_ws;
    unsigned short* xb   = (unsigned short*)((char*)d_ws + weff_bytes);
    const int conv_blocks = (int)((MTOK * (size_t)IN_F) / (256 * 8));  // 16384
    prep_kernel<<<MERGE_BLKS + conv_blocks, 256, 0, stream>>>(x, W, lA, lB, Weff, xb);
    gemm8p_kernel<<<(MTOK / 256) * (OUT_F / 256), 512, 0, stream>>>(xb, Weff, out);
  } else if (ws_size >= weff_bytes) {
    unsigned short* Weff = (unsigned short*)d_ws;
    prep_kernel<<<MERGE_BLKS, 256, 0, stream>>>(x, W, lA, lB, Weff, (unsigned short*)0);
    gemm_f32x_kernel<<<(MTOK / 128) * (OUT_F / 128), 256, 0, stream>>>(x, Weff, out);
  } else {
    float* r = (float*)d_ws;
    lora_r_kernel<<<(MTOK * RANK) / 256, 256, 0, stream>>>(x, lA, r);
    naive_out_kernel<<<(size_t)MTOK * OUT_F / 256, 256, 0, stream>>>(x, W, lB, r, out);
  }
}

// Round 16
// 295.978 us; speedup vs baseline: 1.0078x; 1.0078x over previous
//
#include <hip/hip_runtime.h>
#include <stdint.h>
#include <stddef.h>

#define IN_F    4096
#define OUT_F   4096
#define MTOK    8192      // 4 * 2048 tokens
#define RANK    16
#define SCALING 2.0f      // alpha/rank = 32/16

typedef __attribute__((ext_vector_type(8))) short          bf16x8;
typedef __attribute__((ext_vector_type(4))) float          f32x4;
typedef __attribute__((ext_vector_type(4))) float          fl4;
typedef __attribute__((ext_vector_type(4))) unsigned short u16x4;
typedef __attribute__((ext_vector_type(8))) unsigned short u16x8;

static __device__ __forceinline__ unsigned short f2bf(float f) {
  union { float f; uint32_t u; } v; v.f = f;
  return (unsigned short)((v.u + 0x7fffu + ((v.u >> 16) & 1u)) >> 16);  // RNE
}

static __device__ __forceinline__ void gload16(const void* g, void* l) {
  __builtin_amdgcn_global_load_lds(
      (const __attribute__((address_space(1))) uint32_t*)g,
      (__attribute__((address_space(3))) uint32_t*)l,
      16, 0, 0);
}

// raw s_barrier is IntrNoMem -> fence with sched_barrier(0) on both sides
#define SBAR() __builtin_amdgcn_sched_barrier(0)
#define BARRIER() do { SBAR(); __builtin_amdgcn_s_barrier(); SBAR(); } while (0)

// ---------------------------------------------------------------------------
// fused prep: blocks [0, OUT_F/4) merge 4 W-rows each -> Weff bf16;
//             blocks [OUT_F/4, ...) convert x f32 -> bf16
// ---------------------------------------------------------------------------
#define MERGE_BLKS (OUT_F / 4)   // 1024

__global__ void prep_kernel(const float* __restrict__ x,
                            const float* __restrict__ W,
                            const float* __restrict__ lA,
                            const float* __restrict__ lB,
                            unsigned short* __restrict__ Weff,
                            unsigned short* __restrict__ xb) {
  __shared__ float Bs[4][RANK];
  if (blockIdx.x < MERGE_BLKS) {
    const int o0 = blockIdx.x * 4;
    if (threadIdx.x < 4 * RANK)
      Bs[threadIdx.x >> 4][threadIdx.x & 15] =
          lB[o0 * RANK + threadIdx.x] * SCALING;
    __syncthreads();
#pragma unroll
    for (int it = 0; it < 4; ++it) {
      const int c = threadIdx.x * 4 + it * 1024;
      fl4 w0 = *(const fl4*)(W + (size_t)(o0 + 0) * IN_F + c);
      fl4 w1 = *(const fl4*)(W + (size_t)(o0 + 1) * IN_F + c);
      fl4 w2 = *(const fl4*)(W + (size_t)(o0 + 2) * IN_F + c);
      fl4 w3 = *(const fl4*)(W + (size_t)(o0 + 3) * IN_F + c);
#pragma unroll
      for (int r = 0; r < RANK; ++r) {
        const fl4 a = *(const fl4*)(lA + (size_t)r * IN_F + c);
        const float b0 = Bs[0][r], b1 = Bs[1][r], b2 = Bs[2][r], b3 = Bs[3][r];
#pragma unroll
        for (int e = 0; e < 4; ++e) {
          w0[e] += b0 * a[e]; w1[e] += b1 * a[e];
          w2[e] += b2 * a[e]; w3[e] += b3 * a[e];
        }
      }
      u16x4 p0, p1, p2, p3;
#pragma unroll
      for (int e = 0; e < 4; ++e) {
        p0[e] = f2bf(w0[e]); p1[e] = f2bf(w1[e]);
        p2[e] = f2bf(w2[e]); p3[e] = f2bf(w3[e]);
      }
      *(u16x4*)(Weff + (size_t)(o0 + 0) * IN_F + c) = p0;
      *(u16x4*)(Weff + (size_t)(o0 + 1) * IN_F + c) = p1;
      *(u16x4*)(Weff + (size_t)(o0 + 2) * IN_F + c) = p2;
      *(u16x4*)(Weff + (size_t)(o0 + 3) * IN_F + c) = p3;
    }
  } else {
    const size_t i = ((size_t)(blockIdx.x - MERGE_BLKS) * 256 + threadIdx.x) * 8;
    const fl4 a = *(const fl4*)(x + i);
    const fl4 b = *(const fl4*)(x + i + 4);
    u16x8 p;
    p[0] = f2bf(a[0]); p[1] = f2bf(a[1]); p[2] = f2bf(a[2]); p[3] = f2bf(a[3]);
    p[4] = f2bf(b[0]); p[5] = f2bf(b[1]); p[6] = f2bf(b[2]); p[7] = f2bf(b[3]);
    *(u16x8*)(xb + i) = p;
  }
}

// ---------------------------------------------------------------------------
// 256x256 tile, BK=64, 8 waves (2Mx4N), m201-style 4-phase discipline.
// Final session state (R13): best proven = 215.8 us gemm, deterministic.
//   t:ph0 reads A0,B0(t)  <- licensed by t-1:ph3 vmcnt(4)+BAR
//   t:ph1 reads B1(t)     <- licensed by t:ph0  vmcnt(4)+BAR
//   t:ph2 reads A1(t)     <- licensed by t:ph1  vmcnt(4)+BAR
//   t:ph3 (no reads; b0 regs still live)  stage A1(t+1); vmcnt(4)+BAR
// ---------------------------------------------------------------------------
__global__ __launch_bounds__(512, 2) void gemm8p_kernel(
    const unsigned short* __restrict__ X,    // [8192][4096] bf16
    const unsigned short* __restrict__ Wf,   // [4096][4096] bf16
    float* __restrict__ Out) {
  __shared__ char lds[131072];
  const int tid  = threadIdx.x;
  const int lane = tid & 63;
  const int wave = tid >> 6;
  const int wr = wave >> 2;            // 0..1 (M half)
  const int wc = wave & 3;             // 0..3 (N strip)
  const int fr = lane & 15;
  const int fq = lane >> 4;

  // XCD chunking: each XCD owns 4 consecutive M-tiles x all 16 N-tiles
  const int bid = blockIdx.x;
  const int tm  = (bid & 7) * 4 + ((bid >> 3) & 3);   // 0..31
  const int tn  = bid >> 5;                           // 0..15
  const int m0 = tm << 8;
  const int n0 = tn << 8;

  const unsigned short* Ag = X  + (size_t)m0 * IN_F;
  const unsigned short* Bg = Wf + (size_t)n0 * IN_F;

  // staging lane constants: window = 8 rows x 64 cols = 1024B, slot = 16B
  const int rIW = lane >> 3;                    // row within 8-row window
  const int csw = ((lane & 7) ^ rIW) << 3;      // pre-swizzled source col (elems)

  // ds_read address parts (bytes)
  const int aBase = wr * 16384 + fr * 128;
  const int bBase = 65536 + (wc >> 1) * 16384 + (wc & 1) * 8192 + fr * 128;
  const int cA0 = (fq << 4) ^ ((fr & 7) << 4);  // kk=0 swizzled colbyte
  const int cA1 = cA0 ^ 64;                     // kk=1

  // A chunk C: each wave stages 16 rows of its half-interleaved chunk
#define STAGE_A(C, BUF, K) do {                                                \
    const int _rh = (C) * 64 + (wave & 3) * 16;                                \
    const int _r0 = (wave >> 2) * 128 + _rh + rIW;                             \
    char* _d = lds + (BUF) * 32768 + (wave >> 2) * 16384 + _rh * 128 +         \
               (lane << 4);                                                    \
    gload16(Ag + (size_t)_r0 * IN_F + (K) + csw, _d);                          \
    gload16(Ag + (size_t)(_r0 + 8) * IN_F + (K) + csw, _d + 1024);             \
  } while (0)

  // B chunk C: strip = wave>>1; rows C*32 + (wave&1)*16 .. +15 of that strip
#define STAGE_B(C, BUF, K) do {                                                \
    const int _s  = wave >> 1;                                                 \
    const int _rh = (_s & 1) * 64 + (C) * 32 + (wave & 1) * 16;                \
    const int _r0 = (_s >> 1) * 128 + _rh + rIW;                               \
    char* _d = lds + 65536 + (BUF) * 32768 + (_s >> 1) * 16384 + _rh * 128 +   \
               (lane << 4);                                                    \
    gload16(Bg + (size_t)_r0 * IN_F + (K) + csw, _d);                          \
    gload16(Bg + (size_t)(_r0 + 8) * IN_F + (K) + csw, _d + 1024);             \
  } while (0)

#define LDA(BUF, M, KK) (*(const bf16x8*)(lds + (BUF) * 32768 + aBase + (M) * 2048 + (KK)))
#define LDB(BUF, N, KK) (*(const bf16x8*)(lds + (BUF) * 32768 + bBase + (N) * 2048 + (KK)))

#define MFMA_Q(MB, NB, BR)                                                     \
  _Pragma("unroll")                                                            \
  for (int mi = 0; mi < 4; ++mi)                                               \
    _Pragma("unroll")                                                          \
    for (int ni = 0; ni < 2; ++ni) {                                           \
      acc[(MB)+mi][(NB)+ni] = __builtin_amdgcn_mfma_f32_16x16x32_bf16(a[mi*2],   BR[ni*2],   acc[(MB)+mi][(NB)+ni], 0, 0, 0); \
      acc[(MB)+mi][(NB)+ni] = __builtin_amdgcn_mfma_f32_16x16x32_bf16(a[mi*2+1], BR[ni*2+1], acc[(MB)+mi][(NB)+ni], 0, 0, 0); \
    }

  // BU = compile-time buffer of tile t; NB = BU^1; KN = k of t+1; PF bool
#define TILE(BU, NB, KN, PF)                                                   \
  do {                                                                         \
    /* ---- ph0: reads A-h0 + b0; stage A0(t+1); vmcnt; BAR; Q00 ---- */       \
    _Pragma("unroll")                                                          \
    for (int mi = 0; mi < 4; ++mi) { a[mi*2] = LDA(BU, mi, cA0); a[mi*2+1] = LDA(BU, mi, cA1); } \
    _Pragma("unroll")                                                          \
    for (int ni = 0; ni < 2; ++ni) { b0[ni*2] = LDB(BU, ni, cA0); b0[ni*2+1] = LDB(BU, ni, cA1); } \
    if (PF) { STAGE_A(0, NB, KN);                                              \
              asm volatile("s_waitcnt vmcnt(4)" ::: "memory"); }               \
    else    { asm volatile("s_waitcnt vmcnt(2)" ::: "memory"); }               \
    BARRIER();                                                                 \
    __builtin_amdgcn_s_setprio(1);                                             \
    MFMA_Q(0, 0, b0)                                                           \
    __builtin_amdgcn_s_setprio(0);                                             \
    /* ---- ph1: reads b1; stage B0(t+1); vmcnt; BAR; Q01 ---- */              \
    _Pragma("unroll")                                                          \
    for (int ni = 0; ni < 2; ++ni) { b1[ni*2] = LDB(BU, 2+ni, cA0); b1[ni*2+1] = LDB(BU, 2+ni, cA1); } \
    if (PF) { STAGE_B(0, NB, KN);                                              \
              asm volatile("s_waitcnt vmcnt(4)" ::: "memory"); }               \
    else    { asm volatile("s_waitcnt vmcnt(0)" ::: "memory"); }               \
    BARRIER();                                                                 \
    __builtin_amdgcn_s_setprio(1);                                             \
    MFMA_Q(0, 2, b1)                                                           \
    __builtin_amdgcn_s_setprio(0);                                             \
    /* ---- ph2: reads A-h1; stage B1(t+1); BAR; Q11 ---- */                   \
    _Pragma("unroll")                                                          \
    for (int mi = 0; mi < 4; ++mi) { a[mi*2] = LDA(BU, 4+mi, cA0); a[mi*2+1] = LDA(BU, 4+mi, cA1); } \
    if (PF) STAGE_B(1, NB, KN);                                                \
    BARRIER();                                                                 \
    __builtin_amdgcn_s_setprio(1);                                             \
    MFMA_Q(4, 2, b1)                                                           \
    __builtin_amdgcn_s_setprio(0);                                             \
    /* ---- ph3: no reads (b0 still live); stage A1(t+1); vmcnt; BAR; Q10 ---- */ \
    if (PF) { STAGE_A(1, NB, KN);                                              \
              asm volatile("s_waitcnt vmcnt(4)" ::: "memory"); }               \
    BARRIER();                                                                 \
    __builtin_amdgcn_s_setprio(1);                                             \
    MFMA_Q(4, 0, b0)                                                           \
    __builtin_amdgcn_s_setprio(0);                                             \
  } while (0)

  f32x4 acc[8][4];
#pragma unroll
  for (int i = 0; i < 8; ++i)
#pragma unroll
    for (int j = 0; j < 4; ++j) acc[i][j] = (f32x4){0.f, 0.f, 0.f, 0.f};

  bf16x8 a[8], b0[4], b1[4];

  // prologue: tile 0 -> buf 0, steady-state issue order [A0, B0, B1, A1];
  // pre-loop vmcnt(4) ensures A0,B0(t0) landed before ph0's reads.
  STAGE_A(0, 0, 0); STAGE_B(0, 0, 0); STAGE_B(1, 0, 0); STAGE_A(1, 0, 0);
  asm volatile("s_waitcnt vmcnt(4)" ::: "memory");
  BARRIER();

  for (int tt = 0; tt < 32; ++tt) {
    const int k1 = (tt << 7) + 64;        // always < IN_F
    const int k2 = k1 + 64;               // == IN_F at tt==31
    TILE(0, 1, k1, true);
    TILE(1, 0, k2, (k2 < IN_F));
  }

  // ---- epilogue: C[row = m*16+fq*4+j][col = n*16+fr] ----
#pragma unroll
  for (int mi = 0; mi < 8; ++mi) {
    const int row0 = m0 + wr * 128 + mi * 16 + fq * 4;
#pragma unroll
    for (int ni = 0; ni < 4; ++ni) {
      const int col = n0 + wc * 64 + ni * 16 + fr;
#pragma unroll
      for (int j = 0; j < 4; ++j)
        Out[(size_t)(row0 + j) * OUT_F + col] = acc[mi][ni][j];
    }
  }
#undef STAGE_A
#undef STAGE_B
#undef LDA
#undef LDB
#undef MFMA_Q
#undef TILE
}

// ---------------------------------------------------------------------------
// mid-ws fallback: 128^2 m97-structure GEMM reading f32 x directly
// ---------------------------------------------------------------------------
__global__ __launch_bounds__(256) void gemm_f32x_kernel(
    const float* __restrict__ X,
    const unsigned short* __restrict__ Weff,
    float* __restrict__ Out) {
  __shared__ unsigned short As[128][32];
  __shared__ unsigned short Bs[128][32];

  const int tid  = threadIdx.x;
  const int lane = tid & 63;
  const int wave = tid >> 6;
  const int wr = wave >> 1, wc = wave & 1;
  const int fr = lane & 15, fq = lane >> 4;

  const int bid = blockIdx.x;
  const int m0 = (bid & 63) * 128;
  const int n0 = (bid >> 6) * 128;

  f32x4 acc[4][4];
#pragma unroll
  for (int i = 0; i < 4; ++i)
#pragma unroll
    for (int j = 0; j < 4; ++j) acc[i][j] = (f32x4){0.f, 0.f, 0.f, 0.f};

  const int srow = tid >> 2;
  const int sseg = tid & 3;

  for (int k0 = 0; k0 < IN_F; k0 += 32) {
    if (k0) __syncthreads();
    {
      const unsigned short* gB = Weff + (size_t)(n0 + srow) * IN_F + k0 + sseg * 8;
      gload16(gB, &Bs[srow][sseg * 8]);
      gload16(gB + (size_t)64 * IN_F, &Bs[64 + srow][sseg * 8]);
    }
#pragma unroll
    for (int it = 0; it < 4; ++it) {
      const int c   = tid + it * 256;
      const int row = c >> 3;
      const int c4  = (c & 7) * 4;
      const fl4 v = *(const fl4*)(X + (size_t)(m0 + row) * IN_F + k0 + c4);
      u16x4 p;
      p[0] = f2bf(v[0]); p[1] = f2bf(v[1]); p[2] = f2bf(v[2]); p[3] = f2bf(v[3]);
      *(u16x4*)&As[row][c4] = p;
    }
    __syncthreads();

    bf16x8 af[4], bfm[4];
#pragma unroll
    for (int m = 0; m < 4; ++m)
      af[m] = *(const bf16x8*)&As[wr * 64 + m * 16 + fr][fq * 8];
#pragma unroll
    for (int n = 0; n < 4; ++n)
      bfm[n] = *(const bf16x8*)&Bs[wc * 64 + n * 16 + fr][fq * 8];
#pragma unroll
    for (int m = 0; m < 4; ++m)
#pragma unroll
      for (int n = 0; n < 4; ++n)
        acc[m][n] = __builtin_amdgcn_mfma_f32_16x16x32_bf16(af[m], bfm[n], acc[m][n], 0, 0, 0);
  }

#pragma unroll
  for (int m = 0; m < 4; ++m) {
    const int row0 = m0 + wr * 64 + m * 16 + fq * 4;
#pragma unroll
    for (int n = 0; n < 4; ++n) {
      const int col = n0 + wc * 64 + n * 16 + fr;
#pragma unroll
      for (int j = 0; j < 4; ++j)
        Out[(size_t)(row0 + j) * OUT_F + col] = acc[m][n][j];
    }
  }
}

// ---------------------------------------------------------------------------
// never-path fallbacks (tiny ws)
// ---------------------------------------------------------------------------
__global__ void lora_r_kernel(const float* __restrict__ x,
                              const float* __restrict__ lA,
                              float* __restrict__ r) {
  const int idx = blockIdx.x * 256 + threadIdx.x;
  const int m = idx / RANK, rr = idx % RANK;
  float acc = 0.f;
  for (int k = 0; k < IN_F; ++k)
    acc += x[(size_t)m * IN_F + k] * lA[(size_t)rr * IN_F + k];
  r[idx] = acc * SCALING;
}

__global__ void naive_out_kernel(const float* __restrict__ x,
                                 const float* __restrict__ W,
                                 const float* __restrict__ lB,
                                 const float* __restrict__ r,
                                 float* __restrict__ out) {
  const size_t idx = (size_t)blockIdx.x * 256 + threadIdx.x;
  const int m = (int)(idx / OUT_F), n = (int)(idx % OUT_F);
  float acc = 0.f;
  for (int k = 0; k < IN_F; ++k)
    acc += x[(size_t)m * IN_F + k] * W[(size_t)n * IN_F + k];
#pragma unroll
  for (int rr = 0; rr < RANK; ++rr)
    acc += r[(size_t)m * RANK + rr] * lB[(size_t)n * RANK + rr];
  out[idx] = acc;
}

// ---------------------------------------------------------------------------
extern "C" void kernel_launch(void* const* d_in, const int* in_sizes, int n_in,
                              void* d_out, int out_size, void* d_ws, size_t ws_size,
                              hipStream_t stream) {
  const float* x  = (const float*)d_in[0];
  const float* W  = (const float*)d_in[1];
  const float* lA = (const float*)d_in[2];
  const float* lB = (const float*)d_in[3];
  float* out = (float*)d_out;

  const size_t weff_bytes = (size_t)OUT_F * IN_F * 2;   // 32 MiB
  const size_t xb_bytes   = (size_t)MTOK * IN_F * 2;    // 64 MiB

  if (ws_size >= weff_bytes + xb_bytes) {
    unsigned short* Weff = (unsigned short*)d_ws;
    unsigned short* xb   = (unsigned short*)((char*)d_ws + weff_bytes);
    const int conv_blocks = (int)((MTOK * (size_t)IN_F) / (256 * 8));  // 16384
    prep_kernel<<<MERGE_BLKS + conv_blocks, 256, 0, stream>>>(x, W, lA, lB, Weff, xb);
    gemm8p_kernel<<<(MTOK / 256) * (OUT_F / 256), 512, 0, stream>>>(xb, Weff, out);
  } else if (ws_size >= weff_bytes) {
    unsigned short* Weff = (unsigned short*)d_ws;
    prep_kernel<<<MERGE_BLKS, 256, 0, stream>>>(x, W, lA, lB, Weff, (unsigned short*)0);
    gemm_f32x_kernel<<<(MTOK / 128) * (OUT_F / 128), 256, 0, stream>>>(x, Weff, out);
  } else {
    float* r = (float*)d_ws;
    lora_r_kernel<<<(MTOK * RANK) / 256, 256, 0, stream>>>(x, lA, r);
    naive_out_kernel<<<(size_t)MTOK * OUT_F / 256, 256, 0, stream>>>(x, W, lB, r, out);
  }
}